// Round 6
// baseline (480.596 us; speedup 1.0000x reference)
//
#include <hip/hip_runtime.h>
#include <hip/hip_bf16.h>
#include <stdint.h>

// out = x @ W'^T + bias, W' = FWHT(W rows)/sqrt(n)  (H symmetric, folded into W)
// x (4,2048,8192) f32 -> M=8192, K=8192 ; W (2048,8192) -> N=2048 ; out f32.

#define M_TOTAL 8192
#define K_TOTAL 8192
#define N_TOTAL 2048
#define D_IN 8192

typedef __attribute__((ext_vector_type(8))) short short8;
typedef __attribute__((ext_vector_type(4))) float f32x4;

typedef __attribute__((address_space(1))) void void_g;
typedef __attribute__((address_space(3))) void void_l;
typedef __attribute__((address_space(3))) short lds_s3;

__device__ __forceinline__ short f2bf(float f) {
  __hip_bfloat16 h = __float2bfloat16(f);
  return *reinterpret_cast<short*>(&h);
}

// ---------------- kernel 1: x fp32 -> bf16 ----------------
__global__ void cvt_x_kernel(const float* __restrict__ x, short* __restrict__ xb, long n) {
  long stride = (long)gridDim.x * blockDim.x * 8;
  for (long i = ((long)blockIdx.x * blockDim.x + threadIdx.x) * 8; i < n; i += stride) {
    float4 v0 = *(const float4*)(x + i);
    float4 v1 = *(const float4*)(x + i + 4);
    short8 o;
    o[0] = f2bf(v0.x); o[1] = f2bf(v0.y); o[2] = f2bf(v0.z); o[3] = f2bf(v0.w);
    o[4] = f2bf(v1.x); o[5] = f2bf(v1.y); o[6] = f2bf(v1.z); o[7] = f2bf(v1.w);
    *(short8*)(xb + i) = o;
  }
}

// ---------------- kernel 2: W' = FWHT(W rows) / sqrt(n), bf16 ----------------
__global__ void fwht_w_kernel(const float* __restrict__ W, short* __restrict__ Wh) {
  __shared__ float buf[D_IN];
  const int row = blockIdx.x;
  const float* src = W + (long)row * D_IN;
  for (int i = threadIdx.x; i < D_IN / 4; i += blockDim.x)
    ((float4*)buf)[i] = ((const float4*)src)[i];
  for (int h = 1; h < D_IN; h <<= 1) {
    __syncthreads();
    for (int p = threadIdx.x; p < D_IN / 2; p += blockDim.x) {
      int i = ((p & ~(h - 1)) << 1) | (p & (h - 1));
      float a = buf[i], b = buf[i + h];
      buf[i] = a + b;
      buf[i + h] = a - b;
    }
  }
  __syncthreads();
  const float s = 0.011048543456039806f; // 1/sqrt(8192)
  short* dst = Wh + (long)row * D_IN;
  for (int i = threadIdx.x; i < D_IN; i += blockDim.x)
    dst[i] = f2bf(buf[i] * s);
}

// ---------------- kernel 3: 256x256, BK=32, frag-pipelined bf16 GEMM -------------
// 512 threads = 8 waves (2M x 4N). LDS ring: 4 bufs x (A 16KB + B 16KB) = 128 KiB.
// Chunk-major slot layout [kb4][row][8] -> 0 bank conflicts (verified R2-R5).
// NEW: fragment-register pipelining one phase ahead so the LDS read drain
// (96KB/tile ~= MFMA time) overlaps MFMA instead of serializing with it:
//   ph0: issue am1 reads(slot t)   ; stage A(t+3); lgkm(4);  MFMA mh0 (am0,b[p])
//        FENCE: vmcnt(6)+barrier   (validates slot t+1; per-wave VMEM ledger:
//        outstanding A/B(t+1),A/B(t+2),A(t+3) = 10 -> drain 4 oldest = slot t+1)
//   ph1: issue b/am0 reads(slot t+1); stage B(t+3); lgkm(8); MFMA mh1 (am1,b[p])
//        barrier (WAR guard: slot (t-1) reads complete before its re-staging)
// lgkm ledger: ph0: 8 old + 4 new = 12 -> lgkm(4) drains the 8 prior (in-order DS).
//              ph1: 4 old + 8 new = 12 -> lgkm(8) drains am1.
#define BM 256
#define BN 256
#define BK 32
#define NKT (K_TOTAL / BK) // 256

#define ASL(B) ((B) << 13)
#define BSL(B) (32768 + ((B) << 13))

#define SBAR __builtin_amdgcn_sched_barrier(0)

#define FEN6 do { SBAR; asm volatile("s_waitcnt vmcnt(6)"); SBAR; __builtin_amdgcn_s_barrier(); SBAR; } while (0)
#define FEN4 do { SBAR; asm volatile("s_waitcnt vmcnt(4)"); SBAR; __builtin_amdgcn_s_barrier(); SBAR; } while (0)
#define FEN0 do { SBAR; asm volatile("s_waitcnt vmcnt(0)"); SBAR; __builtin_amdgcn_s_barrier(); SBAR; } while (0)
#define FENB do { SBAR; __builtin_amdgcn_s_barrier(); SBAR; } while (0)

// stage one 256x32 slot: 2 x global_load_lds(16B) per thread (layout as R2-R5)
#define STAGE(SLOTBASE, SRC, KCOL)                                                                \
  __builtin_amdgcn_global_load_lds((void_g*)((SRC) + (KCOL)),                                     \
                                   (void_l*)&lds[(SLOTBASE) + sdst], 16, 0, 0);                   \
  __builtin_amdgcn_global_load_lds((void_g*)((SRC) + (KCOL) + 16),                                \
                                   (void_l*)&lds[(SLOTBASE) + sdst + 4096], 16, 0, 0);

#define DSR(dst, ADDR, IMM)                                                                       \
  asm volatile("ds_read_b128 %0, %1 offset:%2" : "=v"(dst) : "v"(ADDR), "i"(IMM))

#define RD_AM1(S)                                                                                 \
  DSR(am1[0], aAd[S], 1024); DSR(am1[1], aAd[S], 1280);                                           \
  DSR(am1[2], aAd[S], 1536); DSR(am1[3], aAd[S], 1792);

#define RD_AM0(S)                                                                                 \
  DSR(am0[0], aAd[S], 0); DSR(am0[1], aAd[S], 256);                                               \
  DSR(am0[2], aAd[S], 512); DSR(am0[3], aAd[S], 768);

#define RD_B(NP, S)                                                                               \
  DSR(b[NP][0], bAd[S], 0); DSR(b[NP][1], bAd[S], 256);                                           \
  DSR(b[NP][2], bAd[S], 512); DSR(b[NP][3], bAd[S], 768);

#define MFMA0(P)                                                                                  \
  __builtin_amdgcn_s_setprio(1);                                                                  \
  _Pragma("unroll") for (int m = 0; m < 4; ++m) {                                                 \
    _Pragma("unroll") for (int n = 0; n < 4; ++n)                                                 \
        acc[0][m][n] =                                                                            \
            __builtin_amdgcn_mfma_f32_16x16x32_bf16(am0[m], b[P][n], acc[0][m][n], 0, 0, 0);      \
  }                                                                                               \
  __builtin_amdgcn_s_setprio(0);

#define MFMA1(P)                                                                                  \
  __builtin_amdgcn_s_setprio(1);                                                                  \
  _Pragma("unroll") for (int m = 0; m < 4; ++m) {                                                 \
    _Pragma("unroll") for (int n = 0; n < 4; ++n)                                                 \
        acc[1][m][n] =                                                                            \
            __builtin_amdgcn_mfma_f32_16x16x32_bf16(am1[m], b[P][n], acc[1][m][n], 0, 0, 0);      \
  }                                                                                               \
  __builtin_amdgcn_s_setprio(0);

// S: slot t&3; NS: (t+1)&3; PS: (t+3)&3; P: t&1; NP: (t+1)&1
#define TILE(S, NS, PS, P, NP, STG, KP, FENCE, LAST)                                              \
  {                                                                                               \
    if (STG) { STAGE(ASL(PS), aS, (KP)); }                                                        \
    SBAR;                                                                                         \
    RD_AM1(S);                                                                                    \
    SBAR;                                                                                         \
    asm volatile("s_waitcnt lgkmcnt(4)");                                                         \
    SBAR;                                                                                         \
    MFMA0(P);                                                                                     \
    FENCE;                                                                                        \
    if (STG) { STAGE(BSL(PS), bS, (KP)); }                                                        \
    SBAR;                                                                                         \
    if (!LAST) { RD_B(NP, NS); RD_AM0(NS); }                                                      \
    SBAR;                                                                                         \
    if (LAST) { asm volatile("s_waitcnt lgkmcnt(0)"); }                                           \
    else      { asm volatile("s_waitcnt lgkmcnt(8)"); }                                           \
    SBAR;                                                                                         \
    MFMA1(P);                                                                                     \
    SBAR;                                                                                         \
    __builtin_amdgcn_s_barrier();                                                                 \
    SBAR;                                                                                         \
  }

__global__ __launch_bounds__(512, 2) void gemm_kernel(const short* __restrict__ A,
                                                      const short* __restrict__ B,
                                                      const float* __restrict__ bias,
                                                      float* __restrict__ C) {
  __shared__ __attribute__((aligned(16))) short lds[65536]; // 128 KiB

  const int tid = threadIdx.x;
  const int l = tid & 63;
  const int w = tid >> 6;
  const int wm = w >> 2;  // 0..1
  const int wn = w & 3;   // 0..3
  const int lr = l & 15;
  const int lq = l >> 4;

  // XCD-aware bijective swizzle (nwg = 256)
  const int bid = blockIdx.x;
  const int swz = (bid & 7) * 32 + (bid >> 3);
  const int bm = swz >> 3;
  const int bn = swz & 7;
  const long tileM = (long)bm * BM;
  const long tileN = (long)bn * BN;

  const int sdst = tid * 8;
  const short* aS = A + (tileM + (tid & 255)) * (long)K_TOTAL + (tid >> 8) * 8;
  const short* bS = B + (tileN + (tid & 255)) * (long)K_TOTAL + (tid >> 8) * 8;

  const int aoff = lq * 2048 + (wm * 128 + lr) * 8; // shorts within A slot
  const int boff = lq * 2048 + (wn * 64 + lr) * 8;  // shorts within B slot

  const unsigned ldsbase = (unsigned)(uintptr_t)(lds_s3*)&lds[0];
  unsigned aAd[4], bAd[4];
#pragma unroll
  for (int s_ = 0; s_ < 4; ++s_) {
    aAd[s_] = ldsbase + (unsigned)(ASL(s_) + aoff) * 2u;
    bAd[s_] = ldsbase + (unsigned)(BSL(s_) + boff) * 2u;
  }

  f32x4 acc[2][4][4];
#pragma unroll
  for (int mh = 0; mh < 2; ++mh)
#pragma unroll
    for (int m = 0; m < 4; ++m)
#pragma unroll
      for (int n = 0; n < 4; ++n)
        acc[mh][m][n] = (f32x4){0.f, 0.f, 0.f, 0.f};

  // prologue: stage tiles 0,1,2 (12 VMEM); validate slot 0; preload tile-0 frags
  STAGE(ASL(0), aS, 0);
  STAGE(BSL(0), bS, 0);
  STAGE(ASL(1), aS, 32);
  STAGE(BSL(1), bS, 32);
  STAGE(ASL(2), aS, 64);
  STAGE(BSL(2), bS, 64);
  SBAR;
  asm volatile("s_waitcnt vmcnt(8)");
  SBAR;
  __builtin_amdgcn_s_barrier();
  SBAR;

  short8 am0[4], am1[4], b[2][4];
  RD_B(0, 0);
  RD_AM0(0);
  SBAR;

  // main loop: t = 0..251 (4x unrolled; S=u, P=u&1 since t4 % 4 == 0)
  for (int t4 = 0; t4 < NKT - 4; t4 += 4) {
    const int kp0 = (t4 + 3) * BK;
    TILE(0, 1, 3, 0, 1, true, kp0, FEN6, false);
    TILE(1, 2, 0, 1, 0, true, kp0 + BK, FEN6, false);
    TILE(2, 3, 1, 0, 1, true, kp0 + 2 * BK, FEN6, false);
    TILE(3, 0, 2, 1, 0, true, kp0 + 3 * BK, FEN6, false);
  }
  // tails: t = 252 (stages tile 255), 253, 254, 255
  TILE(0, 1, 3, 0, 1, true, 255 * BK, FEN6, false);
  TILE(1, 2, 0, 1, 0, false, 0, FEN4, false);
  TILE(2, 3, 0, 0, 1, false, 0, FEN0, false);
  TILE(3, 0, 0, 1, 0, false, 0, FENB, true);

  // epilogue: C = acc + bias
  const int rb0 = (int)tileM + wm * 128 + lq * 4;
  const int cb0 = (int)tileN + wn * 64 + lr;
#pragma unroll
  for (int mh = 0; mh < 2; ++mh)
#pragma unroll
    for (int n = 0; n < 4; ++n) {
      float bv = bias[cb0 + n * 16];
#pragma unroll
      for (int m = 0; m < 4; ++m) {
        const int r0 = rb0 + mh * 64 + m * 16;
#pragma unroll
        for (int r = 0; r < 4; ++r)
          C[(long)(r0 + r) * N_TOTAL + cb0 + n * 16] = acc[mh][m][n][r] + bv;
      }
    }
}

extern "C" void kernel_launch(void* const* d_in, const int* in_sizes, int n_in,
                              void* d_out, int out_size, void* d_ws, size_t ws_size,
                              hipStream_t stream) {
  const float* x = (const float*)d_in[0];
  const float* W = (const float*)d_in[1];
  const float* bias = (const float*)d_in[2];
  float* out = (float*)d_out;

  short* xb = (short*)d_ws;                                          // 134 MB
  short* wh = (short*)((char*)d_ws + (size_t)M_TOTAL * K_TOTAL * 2); // 33.5 MB

  cvt_x_kernel<<<2048, 256, 0, stream>>>(x, xb, (long)M_TOTAL * K_TOTAL);
  fwht_w_kernel<<<N_TOTAL, 256, 0, stream>>>(W, wh);

  const int grid = (M_TOTAL / BM) * (N_TOTAL / BN); // 256
  gemm_kernel<<<grid, 512, 0, stream>>>(xb, wh, bias, out);
}

// Round 7
// 407.104 us; speedup vs baseline: 1.1805x; 1.1805x over previous
//
#include <hip/hip_runtime.h>
#include <hip/hip_bf16.h>
#include <stdint.h>

// out = x @ W'^T + bias, W' = FWHT(W rows)/sqrt(n)  (H symmetric, folded into W)
// x (4,2048,8192) f32 -> M=8192, K=8192 ; W (2048,8192) -> N=2048 ; out f32.

#define M_TOTAL 8192
#define K_TOTAL 8192
#define N_TOTAL 2048
#define D_IN 8192

typedef __attribute__((ext_vector_type(8))) short short8;
typedef __attribute__((ext_vector_type(4))) float f32x4;

typedef __attribute__((address_space(1))) void void_g;
typedef __attribute__((address_space(3))) void void_l;

__device__ __forceinline__ short f2bf(float f) {
  __hip_bfloat16 h = __float2bfloat16(f);
  return *reinterpret_cast<short*>(&h);
}

// ---------------- kernel 1: x fp32 -> bf16 ----------------
__global__ void cvt_x_kernel(const float* __restrict__ x, short* __restrict__ xb, long n) {
  long stride = (long)gridDim.x * blockDim.x * 8;
  for (long i = ((long)blockIdx.x * blockDim.x + threadIdx.x) * 8; i < n; i += stride) {
    float4 v0 = *(const float4*)(x + i);
    float4 v1 = *(const float4*)(x + i + 4);
    short8 o;
    o[0] = f2bf(v0.x); o[1] = f2bf(v0.y); o[2] = f2bf(v0.z); o[3] = f2bf(v0.w);
    o[4] = f2bf(v1.x); o[5] = f2bf(v1.y); o[6] = f2bf(v1.z); o[7] = f2bf(v1.w);
    *(short8*)(xb + i) = o;
  }
}

// ---------------- kernel 2: W' = FWHT(W rows) / sqrt(n), bf16 ----------------
__global__ void fwht_w_kernel(const float* __restrict__ W, short* __restrict__ Wh) {
  __shared__ float buf[D_IN];
  const int row = blockIdx.x;
  const float* src = W + (long)row * D_IN;
  for (int i = threadIdx.x; i < D_IN / 4; i += blockDim.x)
    ((float4*)buf)[i] = ((const float4*)src)[i];
  for (int h = 1; h < D_IN; h <<= 1) {
    __syncthreads();
    for (int p = threadIdx.x; p < D_IN / 2; p += blockDim.x) {
      int i = ((p & ~(h - 1)) << 1) | (p & (h - 1));
      float a = buf[i], b = buf[i + h];
      buf[i] = a + b;
      buf[i + h] = a - b;
    }
  }
  __syncthreads();
  const float s = 0.011048543456039806f; // 1/sqrt(8192)
  short* dst = Wh + (long)row * D_IN;
  for (int i = threadIdx.x; i < D_IN; i += blockDim.x)
    dst[i] = f2bf(buf[i] * s);
}

// ---------------- kernel 3: 256x256 8-phase bf16 GEMM (m201-template port) ------
// A [M][K], B [N][K] bf16; C [M][N] f32. 512 thr = 8 waves (2M x 4N), per-wave C
// 128x64. BK=64; iter = 2 K-tiles = 8 phases; phase = one C-quadrant x K=64
// (16 MFMA). LDS 128 KiB: A[2dbuf][2half] + B[2dbuf][2half], half = 128 rows x
// 64 k, chunk-major [8 kchunk][128 row][8] -> 0 bank conflicts (verified R2-R6).
// Stage 1 half-tile (2 x global_load_lds w16) per phase. Counted vmcnt(4) at
// phases 4/8 validates A(t+1)+B(t+1), leaves B(t+2) in flight (never drain 0).
// Stage->buffer only after its last reader phase (A halves: last read ph3 ->
// restaged next sub-iter ph1/2; B halves: last read ph2 -> restaged ph3/4).
#define NT 128 // K-tiles of 64

#define ADST(D, H) (((D) * 2 + (H)) * 8192 + sdst)
#define BDST(D, H) (32768 + ((D) * 2 + (H)) * 8192 + sdst)

#define STG(DST, SRC, KOFF)                                                                       \
  __builtin_amdgcn_global_load_lds((void_g*)((SRC) + (KOFF)), (void_l*)&lds[DST], 16, 0, 0);      \
  __builtin_amdgcn_global_load_lds((void_g*)((SRC) + (KOFF) + 32), (void_l*)&lds[(DST) + 4096],   \
                                   16, 0, 0);

// A frag (mi,ks): aRd(d) + ks*4096 + mi*128 ; B frag (nj,ks): bRd(d) + ks*4096 + nj*128
#define RD_A4(ARD, MIB)                                                                           \
  _Pragma("unroll") for (int mi = 0; mi < 4; ++mi) {                                              \
    am[mi][0] = *(const short8*)&lds[(ARD) + ((MIB) + mi) * 128];                                 \
    am[mi][1] = *(const short8*)&lds[(ARD) + 4096 + ((MIB) + mi) * 128];                          \
  }
#define RD_B2(BRD, NJB)                                                                           \
  _Pragma("unroll") for (int nj = 0; nj < 2; ++nj) {                                              \
    bn[(NJB) + nj][0] = *(const short8*)&lds[(BRD) + ((NJB) + nj) * 128];                         \
    bn[(NJB) + nj][1] = *(const short8*)&lds[(BRD) + 4096 + ((NJB) + nj) * 128];                  \
  }

#define MF(MIB, NJB)                                                                              \
  __builtin_amdgcn_s_setprio(1);                                                                  \
  _Pragma("unroll") for (int mi = 0; mi < 4; ++mi) {                                              \
    _Pragma("unroll") for (int nj = 0; nj < 2; ++nj) {                                            \
      _Pragma("unroll") for (int ks = 0; ks < 2; ++ks) acc[(MIB) + mi][(NJB) + nj] =              \
          __builtin_amdgcn_mfma_f32_16x16x32_bf16(am[mi][ks], bn[(NJB) + nj][ks],                 \
                                                  acc[(MIB) + mi][(NJB) + nj], 0, 0, 0);          \
    }                                                                                             \
  }                                                                                               \
  __builtin_amdgcn_s_setprio(0);

#define BAR __builtin_amdgcn_s_barrier()
#define LG0 asm volatile("s_waitcnt lgkmcnt(0)")

// one K-tile (4 phases). D: dbuf 0/1; STGA/STGB compile-time bools; KA/KB k-offsets
// (shorts); FN: "4" or "0"; DOF: emit fence; LB: emit trailing barrier.
#define KTILE(D, STGA, KA, STGB, KB, FN, DOF, LB)                                                 \
  {                                                                                               \
    /* ph1: quadrant (mi0-3 x nj0-1) */                                                           \
    RD_B2(bRd##D, 0);                                                                             \
    RD_A4(aRd##D, 0);                                                                             \
    if (STGA) { STG(ADST(D ^ 1, 0), aSrc0, KA); }                                                 \
    asm volatile("s_waitcnt lgkmcnt(8)");                                                         \
    BAR; LG0;                                                                                     \
    MF(0, 0);                                                                                     \
    BAR;                                                                                          \
    /* ph2: (mi0-3 x nj2-3) */                                                                    \
    RD_B2(bRd##D, 2);                                                                             \
    if (STGA) { STG(ADST(D ^ 1, 1), aSrc1, KA); }                                                 \
    BAR; LG0;                                                                                     \
    MF(0, 2);                                                                                     \
    BAR;                                                                                          \
    /* ph3: (mi4-7 x nj0-1) */                                                                    \
    RD_A4(aRd##D, 4);                                                                             \
    if (STGB) { STG(BDST(D, 0), bSrc0, KB); }                                                     \
    BAR; LG0;                                                                                     \
    MF(4, 0);                                                                                     \
    BAR;                                                                                          \
    /* ph4: (mi4-7 x nj2-3), fence */                                                             \
    if (STGB) { STG(BDST(D, 1), bSrc1, KB); }                                                     \
    BAR;                                                                                          \
    MF(4, 2);                                                                                     \
    if (DOF) { asm volatile("s_waitcnt vmcnt(" FN ")"); }                                         \
    if (LB) BAR;                                                                                  \
  }

__global__ __launch_bounds__(512, 2) void gemm_kernel(const short* __restrict__ A,
                                                      const short* __restrict__ B,
                                                      const float* __restrict__ bias,
                                                      float* __restrict__ C) {
  __shared__ __attribute__((aligned(16))) short lds[65536]; // 128 KiB

  const int tid = threadIdx.x;
  const int l = tid & 63;
  const int w = tid >> 6;
  const int wm = w >> 2;   // 0..1 (M half)
  const int wn = w & 3;    // 0..3 (N quarter)
  const int wh = wn >> 1;  // B half
  const int w1 = wn & 1;   // within B half

  // XCD-aware bijective swizzle (nwg = 256)
  const int bid = blockIdx.x;
  const int swz = (bid & 7) * 32 + (bid >> 3);
  const int bm = swz >> 3;
  const int bn_ = swz & 7;
  const long tileM = (long)bm * 256;
  const long tileN = (long)bn_ * 256;

  // fragment read bases (shorts)
  const int lanepart = (l >> 4) * 1024 + (l & 15) * 8;
  const int aRd0 = (0 * 2 + wm) * 8192 + lanepart;
  const int aRd1 = (1 * 2 + wm) * 8192 + lanepart;
  const int bRd0 = 32768 + (0 * 2 + wh) * 8192 + lanepart + w1 * 512;
  const int bRd1 = 32768 + (1 * 2 + wh) * 8192 + lanepart + w1 * 512;

  // staging: thread -> (row = tid&127, kchunk = tid>>7); dest = halfbase + tid*8 (+4096)
  const int sdst = tid * 8;
  const short* aSrc0 = A + (tileM + 0 * 128 + (tid & 127)) * (long)K_TOTAL + (tid >> 7) * 8;
  const short* aSrc1 = A + (tileM + 1 * 128 + (tid & 127)) * (long)K_TOTAL + (tid >> 7) * 8;
  const short* bSrc0 = B + (tileN + 0 * 128 + (tid & 127)) * (long)K_TOTAL + (tid >> 7) * 8;
  const short* bSrc1 = B + (tileN + 1 * 128 + (tid & 127)) * (long)K_TOTAL + (tid >> 7) * 8;

  f32x4 acc[8][4];
#pragma unroll
  for (int mi = 0; mi < 8; ++mi)
#pragma unroll
    for (int nj = 0; nj < 4; ++nj)
      acc[mi][nj] = (f32x4){0.f, 0.f, 0.f, 0.f};

  // prologue: A(0), B(0) into d0; B(1) into d1 (12 loads); vmcnt(4) leaves B(1)
  STG(ADST(0, 0), aSrc0, 0);
  STG(ADST(0, 1), aSrc1, 0);
  STG(BDST(0, 0), bSrc0, 0);
  STG(BDST(0, 1), bSrc1, 0);
  STG(BDST(1, 0), bSrc0, 64);
  STG(BDST(1, 1), bSrc1, 64);
  asm volatile("s_waitcnt vmcnt(4)");
  BAR;

  short8 am[4][2], bn[4][2];

  // main: t = 0,2,...,124; sub-d0 stages A(t+1), B(t+2); sub-d1 stages A(t+2), B(t+3)
  for (int t = 0; t < NT - 2; t += 2) {
    KTILE(0, true, (t + 1) * 64, true, (t + 2) * 64, "4", true, true);
    KTILE(1, true, (t + 2) * 64, true, (t + 3) * 64, "4", true, true);
  }
  // tail: t = 126 stages A(127) only, drains; t = 127 compute-only
  KTILE(0, true, 127 * 64, false, 0, "0", true, true);
  KTILE(1, false, 0, false, 0, "0", false, false);

  // epilogue: C = acc + bias
  const int rb = (int)tileM + wm * 128 + (l >> 4) * 4;
  const int cb = (int)tileN + wn * 64 + (l & 15);
#pragma unroll
  for (int mi = 0; mi < 8; ++mi)
#pragma unroll
    for (int nj = 0; nj < 4; ++nj) {
      float bv = bias[cb + nj * 16];
      const int r0 = rb + mi * 16;
#pragma unroll
      for (int r = 0; r < 4; ++r)
        C[(long)(r0 + r) * N_TOTAL + cb + nj * 16] = acc[mi][nj][r] + bv;
    }
}

extern "C" void kernel_launch(void* const* d_in, const int* in_sizes, int n_in,
                              void* d_out, int out_size, void* d_ws, size_t ws_size,
                              hipStream_t stream) {
  const float* x = (const float*)d_in[0];
  const float* W = (const float*)d_in[1];
  const float* bias = (const float*)d_in[2];
  float* out = (float*)d_out;

  short* xb = (short*)d_ws;                                          // 134 MB
  short* wh = (short*)((char*)d_ws + (size_t)M_TOTAL * K_TOTAL * 2); // 33.5 MB

  cvt_x_kernel<<<2048, 256, 0, stream>>>(x, xb, (long)M_TOTAL * K_TOTAL);
  fwht_w_kernel<<<N_TOTAL, 256, 0, stream>>>(W, wh);

  const int grid = (M_TOTAL / 256) * (N_TOTAL / 256); // 256
  gemm_kernel<<<grid, 512, 0, stream>>>(xb, wh, bias, out);
}